// Round 8
// baseline (4374.868 us; speedup 1.0000x reference)
//
#include <hip/hip_runtime.h>

// ---------------- problem constants ----------------
#define T_STEPS 512
#define BATCH_N 256
#define IDIM    128
#define NDIM    1024
#define ODIM    10

// decomposition: 16 batch-groups (16 rows) x 16 n-slices (64 cols) = 256 WGs.
// Sync/transport: device-scope (sc0 sc1) bf16 y double-buffer + per-wave u32
// flags, PACED poll (s_sleep(1)). R3 structure (reg W, reg gather, LDS
// reduction) + R2's proven pacing. No scope tricks (R4/R6 hung), no
// self-tagged re-gather polls (R5/R7 flood).
#define BB   16
#define NS   64
#define THREADS 256
#define GAIN 0.03125f

// ---------------- workspace layout (bytes) ----------------
#define YBUF_OFF    (33554432ull)                 // after bf16 batch [512][256][128]
#define YBUF_HALF   (524288ull)                   // bf16 [16][16][1024] per parity
#define FLG_OFF     (YBUF_OFF + 2*YBUF_HALF)
#define FLG_BYTES   (4096ull)                     // [16 groups][64 waves] u32
#define XT_OFF      (FLG_OFF + FLG_BYTES)
#define XT_BYTES    (1048576ull)                  // fp32 [256][1024]
#define WS_NEED     (XT_OFF + XT_BYTES)

typedef short    s16x8 __attribute__((ext_vector_type(8)));
typedef float    f32x4 __attribute__((ext_vector_type(4)));
typedef unsigned u32x4 __attribute__((ext_vector_type(4)));

__device__ __forceinline__ unsigned short f2bf(float f) {
  unsigned u = __builtin_bit_cast(unsigned, f);
  u += 0x7fffu + ((u >> 16) & 1u);               // RTNE
  return (unsigned short)(u >> 16);
}

// ---------------- batch fp32 -> bf16 prepass ----------------
__global__ void horn_convert(const float* __restrict__ src, unsigned short* __restrict__ dst) {
  size_t gid = (size_t)blockIdx.x * 256 + threadIdx.x;
  const f32x4* s4 = reinterpret_cast<const f32x4*>(src) + gid * 2;
  f32x4 a = s4[0], b = s4[1];
  u32x4 o;
  o[0] = (unsigned)f2bf(a[0]) | ((unsigned)f2bf(a[1]) << 16);
  o[1] = (unsigned)f2bf(a[2]) | ((unsigned)f2bf(a[3]) << 16);
  o[2] = (unsigned)f2bf(b[0]) | ((unsigned)f2bf(b[1]) << 16);
  o[3] = (unsigned)f2bf(b[2]) | ((unsigned)f2bf(b[3]) << 16);
  reinterpret_cast<u32x4*>(dst)[gid] = o;
}

// ---------------- persistent recurrent kernel ----------------
// K-split: wave wv covers K in [wv*256, wv*256+256) for ALL 64 cols of the slice.
// y A-frags gathered straight from MALL into registers (no LDS staging).
// Cross-wave reduction via parity-double-buffered LDS (32 KB), 1 barrier/step.
__launch_bounds__(THREADS, 1)
__global__ void horn_persistent(const unsigned short* __restrict__ batchbf,
                                const float* __restrict__ i2h_w,
                                const float* __restrict__ i2h_b,
                                const float* __restrict__ h2h_w,
                                const float* __restrict__ h2h_b,
                                unsigned short* ybuf,     // [2][16][16][1024] bf16
                                unsigned int*  flags,     // [16][64] u32
                                float* xT)                // [256][1024] fp32
{
  __shared__ f32x4 red[2][16][64];                 // [parity][wv*4+ct][lane]
  const int tid  = threadIdx.x;
  const int lane = tid & 63;
  const int wv   = tid >> 6;          // wave 0..3 (owns K-quarter wv)
  const int blk  = blockIdx.x;
  const int ig   = blk & 15;          // batch group
  const int jg   = blk >> 4;          // n-slice
  const int l15  = lane & 15;
  const int kb   = lane >> 4;         // k-sub within fragment
  const int jc   = jg * NS + wv * 16 + l15;        // column this wave OWNS (state)

  // ---- W fragments: cols jg*64+ct*16+l15, K-quarter wv, pre-scaled by GAIN ----
  s16x8 wfrag[4][8];
  #pragma unroll
  for (int ct = 0; ct < 4; ++ct) {
    #pragma unroll
    for (int q = 0; q < 8; ++q) {
      const float* g = h2h_w + (size_t)(jg * NS + ct * 16 + l15) * NDIM + wv * 256 + q * 32 + kb * 8;
      f32x4 a = *reinterpret_cast<const f32x4*>(g);
      f32x4 b = *reinterpret_cast<const f32x4*>(g + 4);
      s16x8 v;
      v[0] = (short)f2bf(a[0]*GAIN); v[1] = (short)f2bf(a[1]*GAIN);
      v[2] = (short)f2bf(a[2]*GAIN); v[3] = (short)f2bf(a[3]*GAIN);
      v[4] = (short)f2bf(b[0]*GAIN); v[5] = (short)f2bf(b[1]*GAIN);
      v[6] = (short)f2bf(b[2]*GAIN); v[7] = (short)f2bf(b[3]*GAIN);
      wfrag[ct][q] = v;
    }
  }

  // ---- i2h B-fragments + fused bias (for OWNED column jc) ----
  s16x8 i2hf[4];
  #pragma unroll
  for (int kc = 0; kc < 4; ++kc) {
    const float* g = i2h_w + (size_t)jc * IDIM + kc * 32 + kb * 8;
    s16x8 v;
    #pragma unroll
    for (int e = 0; e < 8; ++e) v[e] = (short)f2bf(g[e]);
    i2hf[kc] = v;
  }
  const float bias = i2h_b[jc] + h2h_b[jc] * GAIN;

  // ---- batch fragments for t=0 ----
  s16x8 bfr[4];
  {
    const unsigned short* bp = batchbf + ((size_t)ig * BB + l15) * IDIM + kb * 8;
    #pragma unroll
    for (int kc = 0; kc < 4; ++kc) bfr[kc] = *reinterpret_cast<const s16x8*>(bp + kc * 32);
  }

  // ---- per-lane pointers ----
  const char* ybase = (const char*)ybuf + (size_t)ig * (BB * NDIM * 2)
                      + (size_t)l15 * 2048 + wv * 512 + kb * 16;   // gather base (parity 0)
  unsigned short* wp0 = ybuf + (size_t)ig * (BB * NDIM) + (size_t)(kb * 4) * NDIM + jc; // publish base (parity 0)
  const unsigned int* fpoll = flags + ig * 64 + lane;              // poll: one flag per lane
  unsigned int* fstore = flags + ig * 64 + jg * 4 + wv;            // my wave's flag

  float xs[4] = {0.f,0.f,0.f,0.f};
  float ys[4] = {0.f,0.f,0.f,0.f};

  for (int t = 0; t < T_STEPS; ++t) {
    // ---- poll (PACED): all 64 waves of this group have published y_t ----
    if (t > 0) {
      while (true) {
        unsigned fv;
        asm volatile("global_load_dword %0, %1, off sc0 sc1\n\t"
                     "s_waitcnt vmcnt(0)"
                     : "=v"(fv) : "v"(fpoll) : "memory");
        if (__all((int)fv >= t)) break;
        __builtin_amdgcn_s_sleep(1);
      }
    }

    // ---- issue y-quarter gather straight to A-registers ----
    const char* gp = ybase + (size_t)(t & 1) * YBUF_HALF;
    s16x8 a0, a1, a2, a3, a4, a5, a6, a7;
    asm volatile(
      "global_load_dwordx4 %0, %8, off offset:0   sc0 sc1\n\t"
      "global_load_dwordx4 %1, %8, off offset:64  sc0 sc1\n\t"
      "global_load_dwordx4 %2, %8, off offset:128 sc0 sc1\n\t"
      "global_load_dwordx4 %3, %8, off offset:192 sc0 sc1\n\t"
      "global_load_dwordx4 %4, %8, off offset:256 sc0 sc1\n\t"
      "global_load_dwordx4 %5, %8, off offset:320 sc0 sc1\n\t"
      "global_load_dwordx4 %6, %8, off offset:384 sc0 sc1\n\t"
      "global_load_dwordx4 %7, %8, off offset:448 sc0 sc1"
      : "=&v"(a0), "=&v"(a1), "=&v"(a2), "=&v"(a3),
        "=&v"(a4), "=&v"(a5), "=&v"(a6), "=&v"(a7)
      : "v"(gp) : "memory");

    // ---- u-phase under the gather shadow: uacc = bias + batch_t @ i2h^T ----
    f32x4 uacc = {bias, bias, bias, bias};
    #pragma unroll
    for (int kc = 0; kc < 4; ++kc)
      uacc = __builtin_amdgcn_mfma_f32_16x16x32_bf16(bfr[kc], i2hf[kc], uacc, 0, 0, 0);

    asm volatile("s_waitcnt vmcnt(0)" ::: "memory");
    __builtin_amdgcn_sched_barrier(0);             // keep rec MFMAs below the wait

    // ---- rec partials: acc[ct] += y_quarter @ W^T (all in registers) ----
    f32x4 c0 = {0,0,0,0}, c1 = {0,0,0,0}, c2 = {0,0,0,0}, c3 = {0,0,0,0};
    #define RECQ(aq, q) \
      c0 = __builtin_amdgcn_mfma_f32_16x16x32_bf16(aq, wfrag[0][q], c0, 0, 0, 0); \
      c1 = __builtin_amdgcn_mfma_f32_16x16x32_bf16(aq, wfrag[1][q], c1, 0, 0, 0); \
      c2 = __builtin_amdgcn_mfma_f32_16x16x32_bf16(aq, wfrag[2][q], c2, 0, 0, 0); \
      c3 = __builtin_amdgcn_mfma_f32_16x16x32_bf16(aq, wfrag[3][q], c3, 0, 0, 0);
    RECQ(a0, 0) RECQ(a1, 1) RECQ(a2, 2) RECQ(a3, 3)
    RECQ(a4, 4) RECQ(a5, 5) RECQ(a6, 6) RECQ(a7, 7)
    #undef RECQ

    // ---- cross-wave reduction (parity LDS, contiguous = conflict-free) ----
    const int rp = t & 1;
    red[rp][wv * 4 + 0][lane] = c0;
    red[rp][wv * 4 + 1][lane] = c1;
    red[rp][wv * 4 + 2][lane] = c2;
    red[rp][wv * 4 + 3][lane] = c3;
    __syncthreads();
    f32x4 z4 = uacc;
    z4 += red[rp][0 * 4 + wv][lane];
    z4 += red[rp][1 * 4 + wv][lane];
    z4 += red[rp][2 * 4 + wv][lane];
    z4 += red[rp][3 * 4 + wv][lane];

    // ---- state update (fp32, fast tanh) ----
    unsigned yw0, yw1, yw2, yw3;
    {
      float z, e, r, th, yn;
      z = z4[0]; e = __expf(z + z); r = __builtin_amdgcn_rcpf(e + 1.0f); th = fmaf(-2.0f, r, 1.0f);
      yn = ys[0] + 0.1f*(th - xs[0] - 0.2f*ys[0]); xs[0] += 0.1f*yn; ys[0] = yn; yw0 = f2bf(yn);
      z = z4[1]; e = __expf(z + z); r = __builtin_amdgcn_rcpf(e + 1.0f); th = fmaf(-2.0f, r, 1.0f);
      yn = ys[1] + 0.1f*(th - xs[1] - 0.2f*ys[1]); xs[1] += 0.1f*yn; ys[1] = yn; yw1 = f2bf(yn);
      z = z4[2]; e = __expf(z + z); r = __builtin_amdgcn_rcpf(e + 1.0f); th = fmaf(-2.0f, r, 1.0f);
      yn = ys[2] + 0.1f*(th - xs[2] - 0.2f*ys[2]); xs[2] += 0.1f*yn; ys[2] = yn; yw2 = f2bf(yn);
      z = z4[3]; e = __expf(z + z); r = __builtin_amdgcn_rcpf(e + 1.0f); th = fmaf(-2.0f, r, 1.0f);
      yn = ys[3] + 0.1f*(th - xs[3] - 0.2f*ys[3]); xs[3] += 0.1f*yn; ys[3] = yn; yw3 = f2bf(yn);
    }

    // ---- publish y_{t+1} for OWNED column (4 rows), drain, then flag ----
    {
      unsigned short* b0 = wp0 + (size_t)((t + 1) & 1) * 262144;
      unsigned short* b1 = b0 + 2 * NDIM;
      asm volatile(
        "global_store_short %4, %0, off offset:0    sc0 sc1\n\t"
        "global_store_short %4, %1, off offset:2048 sc0 sc1\n\t"
        "global_store_short %5, %2, off offset:0    sc0 sc1\n\t"
        "global_store_short %5, %3, off offset:2048 sc0 sc1\n\t"
        "s_waitcnt vmcnt(0)"
        :
        : "v"(yw0), "v"(yw1), "v"(yw2), "v"(yw3), "v"(b0), "v"(b1)
        : "memory");
    }
    if (lane == 0) {
      unsigned nv = (unsigned)(t + 1);
      asm volatile("global_store_dword %0, %1, off sc0 sc1"
                   :: "v"(fstore), "v"(nv) : "memory");
    }

    // ---- prefetch batch for t+1 (overlaps next poll) ----
    {
      const int tn = (t + 1 < T_STEPS) ? (t + 1) : t;
      const unsigned short* bp = batchbf + ((size_t)tn * BATCH_N + ig * BB + l15) * IDIM + kb * 8;
      #pragma unroll
      for (int kc = 0; kc < 4; ++kc) bfr[kc] = *reinterpret_cast<const s16x8*>(bp + kc * 32);
    }
  }

  // ---- write x_T (owned column, 4 rows) ----
  #pragma unroll
  for (int q = 0; q < 4; ++q) {
    int row = ig * BB + kb * 4 + q;
    xT[(size_t)row * NDIM + jc] = xs[q];
  }
}

// ---------------- final readout: out = x_T @ h2o^T + b ----------------
__global__ void horn_out(const float* __restrict__ xT, const float* __restrict__ h2o_w,
                         const float* __restrict__ h2o_b, float* __restrict__ out) {
  int b = blockIdx.x;
  int lane = threadIdx.x;                  // 64 threads
  float p[ODIM];
  #pragma unroll
  for (int o = 0; o < ODIM; ++o) p[o] = 0.f;
  for (int it = 0; it < NDIM / 64; ++it) {
    int n = it * 64 + lane;
    float xv = xT[(size_t)b * NDIM + n];
    #pragma unroll
    for (int o = 0; o < ODIM; ++o) p[o] += xv * h2o_w[o * NDIM + n];
  }
  #pragma unroll
  for (int o = 0; o < ODIM; ++o) {
    float v = p[o];
    #pragma unroll
    for (int off = 32; off >= 1; off >>= 1) v += __shfl_down(v, off, 64);
    if (lane == 0) out[b * ODIM + o] = v + h2o_b[o];
  }
}

__global__ void horn_fail(float* out) {    // loud sentinel if ws too small
  int i = blockIdx.x * 256 + threadIdx.x;
  if (i < BATCH_N * ODIM) out[i] = 12345.0f;
}

extern "C" void kernel_launch(void* const* d_in, const int* in_sizes, int n_in,
                              void* d_out, int out_size, void* d_ws, size_t ws_size,
                              hipStream_t stream) {
  const float* batch = (const float*)d_in[0];
  const float* i2h_w = (const float*)d_in[1];
  const float* i2h_b = (const float*)d_in[2];
  const float* h2h_w = (const float*)d_in[3];
  const float* h2h_b = (const float*)d_in[4];
  const float* h2o_w = (const float*)d_in[5];
  const float* h2o_b = (const float*)d_in[6];
  float* out = (float*)d_out;
  char* ws = (char*)d_ws;

  if (ws_size < WS_NEED) {
    horn_fail<<<16, 256, 0, stream>>>(out);
    return;
  }

  hipMemsetAsync(ws + YBUF_OFF, 0, YBUF_HALF, stream);   // y_0 = 0 (parity 0)
  hipMemsetAsync(ws + FLG_OFF, 0, FLG_BYTES, stream);    // flags = 0

  horn_convert<<<8192, 256, 0, stream>>>(batch, (unsigned short*)(ws + 0));

  horn_persistent<<<256, THREADS, 0, stream>>>(
      (const unsigned short*)(ws + 0), i2h_w, i2h_b, h2h_w, h2h_b,
      (unsigned short*)(ws + YBUF_OFF), (unsigned int*)(ws + FLG_OFF),
      (float*)(ws + XT_OFF));

  horn_out<<<BATCH_N, 64, 0, stream>>>((const float*)(ws + XT_OFF), h2o_w, h2o_b, out);
}

// Round 9
// 1877.185 us; speedup vs baseline: 2.3305x; 2.3305x over previous
//
#include <hip/hip_runtime.h>

// ---------------- problem constants ----------------
#define T_STEPS 512
#define BATCH_N 256
#define IDIM    128
#define NDIM    1024
#define ODIM    10

// 128 WGs = 16 batch-groups (16 rows) x 8 col-slices (128 cols), 512 threads =
// 8 waves = 4 K-splits x 2 ct-groups. W in VGPRs (128/lane). y transport:
// bf16, device-scope sc0 sc1, COALESCED cooperative gather -> swizzled LDS
// (R2's proven pattern). Per-WG flags (one 32B line per group), paced poll.
// S=16 (R2) -> S=8 halves the MALL read volume: 8MB -> 4MB per step.
#define THREADS 512
#define GAIN 0.03125f

// ---------------- workspace layout (bytes) ----------------
#define YBUF_OFF    (33554432ull)                 // after bf16 batch [512][256][128]
#define YBUF_HALF   (524288ull)                   // bytes per parity: bf16 [16][16][1024]
#define YHALF_EL    (262144u)                     // ushort elements per parity
#define FLG_OFF     (YBUF_OFF + 2*YBUF_HALF)
#define FLG_BYTES   (1024ull)                     // [16 groups][16 words pad] u32 (8 used)
#define XT_OFF      (FLG_OFF + FLG_BYTES)
#define XT_BYTES    (1048576ull)                  // fp32 [256][1024]
#define WS_NEED     (XT_OFF + XT_BYTES)

typedef short    s16x8 __attribute__((ext_vector_type(8)));
typedef float    f32x4 __attribute__((ext_vector_type(4)));
typedef unsigned u32x4 __attribute__((ext_vector_type(4)));

__device__ __forceinline__ unsigned short f2bf(float f) {
  unsigned u = __builtin_bit_cast(unsigned, f);
  u += 0x7fffu + ((u >> 16) & 1u);               // RTNE
  return (unsigned short)(u >> 16);
}

// ---------------- batch fp32 -> bf16 prepass ----------------
__global__ void horn_convert(const float* __restrict__ src, unsigned short* __restrict__ dst) {
  size_t gid = (size_t)blockIdx.x * 256 + threadIdx.x;
  const f32x4* s4 = reinterpret_cast<const f32x4*>(src) + gid * 2;
  f32x4 a = s4[0], b = s4[1];
  u32x4 o;
  o[0] = (unsigned)f2bf(a[0]) | ((unsigned)f2bf(a[1]) << 16);
  o[1] = (unsigned)f2bf(a[2]) | ((unsigned)f2bf(a[3]) << 16);
  o[2] = (unsigned)f2bf(b[0]) | ((unsigned)f2bf(b[1]) << 16);
  o[3] = (unsigned)f2bf(b[2]) | ((unsigned)f2bf(b[3]) << 16);
  reinterpret_cast<u32x4*>(dst)[gid] = o;
}

// ---------------- persistent recurrent kernel ----------------
// LDS: [0,32768)   y-stage bf16 [16 rows][1024], XOR-swizzled (single buffer)
//      [32768,65536) red[4 ki][8 ct][64 lane] f32x4 (single buffer)
__launch_bounds__(THREADS, 2)     // pin 2 waves/EU -> 256-VGPR budget (R7 spilled at (512,1))
__global__ void horn_persistent(const unsigned short* __restrict__ batchbf,
                                const float* __restrict__ i2h_w,
                                const float* __restrict__ i2h_b,
                                const float* __restrict__ h2h_w,
                                const float* __restrict__ h2h_b,
                                unsigned short* ybuf,     // bf16 [2][16][16][1024]
                                unsigned int*  flags,     // u32 [16][16] (8 used/group)
                                float* xT)                // [256][1024] fp32
{
  extern __shared__ char smem[];
  char*  ylds = smem;                              // 32 KB
  f32x4* red  = (f32x4*)(smem + 32768);            // 32 KB

  const int tid  = threadIdx.x;
  const int lane = tid & 63;
  const int wv   = tid >> 6;           // 0..7
  const int ki   = wv & 3;             // K-quarter [ki*256, ki*256+256)
  const int ci   = wv >> 2;            // ct-group: cts [ci*4, ci*4+4)
  const int g    = blockIdx.x & 15;    // batch group (16 rows)
  const int s    = blockIdx.x >> 4;    // col-slice 0..7 (128 cols)
  const int l15  = lane & 15;
  const int kb   = lane >> 4;
  const int ct_own = ci * 4 + ki;      // this wave's owned ct (bijective over 8)
  const int jc   = s * 128 + ct_own * 16 + l15;    // owned output column

  // ---- W fragments: 4 ct (ci-group) x 8 kc (K-quarter ki), xGAIN = 128 VGPRs ----
  s16x8 wfrag[4][8];
  #pragma unroll
  for (int j = 0; j < 4; ++j) {
    #pragma unroll
    for (int kc = 0; kc < 8; ++kc) {
      const float* gp = h2h_w + (size_t)(s * 128 + (ci * 4 + j) * 16 + l15) * NDIM
                        + ki * 256 + kc * 32 + kb * 8;
      f32x4 a = *reinterpret_cast<const f32x4*>(gp);
      f32x4 b = *reinterpret_cast<const f32x4*>(gp + 4);
      s16x8 v;
      v[0] = (short)f2bf(a[0]*GAIN); v[1] = (short)f2bf(a[1]*GAIN);
      v[2] = (short)f2bf(a[2]*GAIN); v[3] = (short)f2bf(a[3]*GAIN);
      v[4] = (short)f2bf(b[0]*GAIN); v[5] = (short)f2bf(b[1]*GAIN);
      v[6] = (short)f2bf(b[2]*GAIN); v[7] = (short)f2bf(b[3]*GAIN);
      wfrag[j][kc] = v;
    }
  }

  // ---- i2h B-frags for owned column + fused bias ----
  s16x8 i2hf[4];
  #pragma unroll
  for (int kc = 0; kc < 4; ++kc) {
    const float* gp = i2h_w + (size_t)jc * IDIM + kc * 32 + kb * 8;
    s16x8 v;
    #pragma unroll
    for (int e = 0; e < 8; ++e) v[e] = (short)f2bf(gp[e]);
    i2hf[kc] = v;
  }
  const float bias = i2h_b[jc] + GAIN * h2h_b[jc];

  // ---- batch A-frags for t=0 ----
  s16x8 bfr[4];
  {
    const unsigned short* bp = batchbf + ((size_t)g * 16 + l15) * IDIM + kb * 8;
    #pragma unroll
    for (int kc = 0; kc < 4; ++kc) bfr[kc] = *reinterpret_cast<const s16x8*>(bp + kc * 32);
  }

  float xs[4] = {0.f,0.f,0.f,0.f};
  float ys[4] = {0.f,0.f,0.f,0.f};

  const char* ytile = (const char*)ybuf + (size_t)g * 32768;         // + p*YBUF_HALF
  unsigned short* pub0 = ybuf + (size_t)(g * 16 + kb * 4) * 1024 + jc; // + pn*YHALF_EL
  const unsigned* fpoll = flags + g * 16 + (lane & 7);
  unsigned* fstore = flags + g * 16 + s;

  for (int t = 0; t < T_STEPS; ++t) {
    const int p = t & 1, pn = p ^ 1;

    // ---- poll (paced): all 8 slice-WGs of this group published y_t ----
    if (t > 0) {
      while (true) {
        unsigned fv;
        asm volatile("global_load_dword %0, %1, off sc0 sc1\n\t"
                     "s_waitcnt vmcnt(0)"
                     : "=v"(fv) : "v"(fpoll) : "memory");
        if (__all((int)fv >= t)) break;
        __builtin_amdgcn_s_sleep(1);
      }
    }

    // ---- issue COALESCED gather of the 32KB y tile (16B/thread x 4 rounds) ----
    const char* q0 = ytile + (size_t)p * YBUF_HALF + tid * 16;
    u32x4 v0, v1, v2, v3;
    asm volatile(
      "global_load_dwordx4 %0, %4, off sc0 sc1\n\t"
      "global_load_dwordx4 %1, %5, off sc0 sc1\n\t"
      "global_load_dwordx4 %2, %6, off sc0 sc1\n\t"
      "global_load_dwordx4 %3, %7, off sc0 sc1"
      : "=&v"(v0), "=&v"(v1), "=&v"(v2), "=&v"(v3)
      : "v"(q0), "v"(q0 + 8192), "v"(q0 + 16384), "v"(q0 + 24576)
      : "memory");

    // ---- u-phase under the gather shadow: uacc = bias + batch_t @ i2h^T ----
    f32x4 uacc = {bias, bias, bias, bias};
    #pragma unroll
    for (int kc = 0; kc < 4; ++kc)
      uacc = __builtin_amdgcn_mfma_f32_16x16x32_bf16(bfr[kc], i2hf[kc], uacc, 0, 0, 0);

    // ---- prefetch batch for t+1 (absorbed by the same vmcnt) ----
    {
      const int tn = (t + 1 < T_STEPS) ? (t + 1) : t;
      const unsigned short* bp = batchbf + ((size_t)tn * BATCH_N + g * 16 + l15) * IDIM + kb * 8;
      #pragma unroll
      for (int kc = 0; kc < 4; ++kc) bfr[kc] = *reinterpret_cast<const s16x8*>(bp + kc * 32);
    }

    asm volatile("s_waitcnt vmcnt(0)" ::: "memory");
    __builtin_amdgcn_sched_barrier(0);

    // ---- stage to LDS, XOR-swizzled; lane-contiguous 16B = conflict-free ----
    #define STG(r, vr) { int off = tid * 16 + (r) * 8192; int row = off >> 11; \
      *reinterpret_cast<u32x4*>(ylds + (off ^ ((row & 7) << 4))) = vr; }
    STG(0, v0) STG(1, v1) STG(2, v2) STG(3, v3)
    #undef STG
    __syncthreads();                               // bar1: tile ready

    // ---- rec partials: 4 ct x 8 kc MFMAs, A-frags from LDS (1 read / kc) ----
    f32x4 c0 = {0,0,0,0}, c1 = {0,0,0,0}, c2 = {0,0,0,0}, c3 = {0,0,0,0};
    #pragma unroll
    for (int kc = 0; kc < 8; ++kc) {
      int boff = (l15 * 2048 + ki * 512 + kc * 64 + kb * 16) ^ ((l15 & 7) << 4);
      s16x8 a = *reinterpret_cast<const s16x8*>(ylds + boff);
      c0 = __builtin_amdgcn_mfma_f32_16x16x32_bf16(a, wfrag[0][kc], c0, 0, 0, 0);
      c1 = __builtin_amdgcn_mfma_f32_16x16x32_bf16(a, wfrag[1][kc], c1, 0, 0, 0);
      c2 = __builtin_amdgcn_mfma_f32_16x16x32_bf16(a, wfrag[2][kc], c2, 0, 0, 0);
      c3 = __builtin_amdgcn_mfma_f32_16x16x32_bf16(a, wfrag[3][kc], c3, 0, 0, 0);
    }

    // ---- cross-wave K-reduction (4 partials per output) ----
    red[((size_t)ki * 8 + ci * 4 + 0) * 64 + lane] = c0;
    red[((size_t)ki * 8 + ci * 4 + 1) * 64 + lane] = c1;
    red[((size_t)ki * 8 + ci * 4 + 2) * 64 + lane] = c2;
    red[((size_t)ki * 8 + ci * 4 + 3) * 64 + lane] = c3;
    __syncthreads();                               // bar2: partials ready
    f32x4 z = uacc;
    z += red[(0 * 8 + ct_own) * 64 + lane];
    z += red[(1 * 8 + ct_own) * 64 + lane];
    z += red[(2 * 8 + ct_own) * 64 + lane];
    z += red[(3 * 8 + ct_own) * 64 + lane];

    // ---- state update (fp32, fast tanh) ----
    unsigned yw0, yw1, yw2, yw3;
    {
      float zz, e, r, th, yn;
      zz = z[0]; e = __expf(zz + zz); r = __builtin_amdgcn_rcpf(e + 1.0f); th = fmaf(-2.0f, r, 1.0f);
      yn = ys[0] + 0.1f*(th - xs[0] - 0.2f*ys[0]); xs[0] += 0.1f*yn; ys[0] = yn; yw0 = f2bf(yn);
      zz = z[1]; e = __expf(zz + zz); r = __builtin_amdgcn_rcpf(e + 1.0f); th = fmaf(-2.0f, r, 1.0f);
      yn = ys[1] + 0.1f*(th - xs[1] - 0.2f*ys[1]); xs[1] += 0.1f*yn; ys[1] = yn; yw1 = f2bf(yn);
      zz = z[2]; e = __expf(zz + zz); r = __builtin_amdgcn_rcpf(e + 1.0f); th = fmaf(-2.0f, r, 1.0f);
      yn = ys[2] + 0.1f*(th - xs[2] - 0.2f*ys[2]); xs[2] += 0.1f*yn; ys[2] = yn; yw2 = f2bf(yn);
      zz = z[3]; e = __expf(zz + zz); r = __builtin_amdgcn_rcpf(e + 1.0f); th = fmaf(-2.0f, r, 1.0f);
      yn = ys[3] + 0.1f*(th - xs[3] - 0.2f*ys[3]); xs[3] += 0.1f*yn; ys[3] = yn; yw3 = f2bf(yn);
    }

    // ---- publish y_{t+1} (owned col, 4 rows), drain, WG-sync, single flag ----
    {
      unsigned short* b0 = pub0 + (size_t)pn * YHALF_EL;
      unsigned short* b1 = b0 + 2 * NDIM;
      asm volatile(
        "global_store_short %4, %0, off offset:0    sc0 sc1\n\t"
        "global_store_short %4, %1, off offset:2048 sc0 sc1\n\t"
        "global_store_short %5, %2, off offset:0    sc0 sc1\n\t"
        "global_store_short %5, %3, off offset:2048 sc0 sc1\n\t"
        "s_waitcnt vmcnt(0)"
        :
        : "v"(yw0), "v"(yw1), "v"(yw2), "v"(yw3), "v"(b0), "v"(b1)
        : "memory");
    }
    __syncthreads();                               // bar3: all waves drained
    if (tid == 0) {
      unsigned nv = (unsigned)(t + 1);
      asm volatile("global_store_dword %0, %1, off sc0 sc1"
                   :: "v"(fstore), "v"(nv) : "memory");
    }
  }

  // ---- write x_T (owned column, 4 rows) ----
  #pragma unroll
  for (int q = 0; q < 4; ++q) {
    int row = g * 16 + kb * 4 + q;
    xT[(size_t)row * NDIM + jc] = xs[q];
  }
}

// ---------------- final readout: out = x_T @ h2o^T + b ----------------
__global__ void horn_out(const float* __restrict__ xT, const float* __restrict__ h2o_w,
                         const float* __restrict__ h2o_b, float* __restrict__ out) {
  int b = blockIdx.x;
  int lane = threadIdx.x;                  // 64 threads
  float p[ODIM];
  #pragma unroll
  for (int o = 0; o < ODIM; ++o) p[o] = 0.f;
  for (int it = 0; it < NDIM / 64; ++it) {
    int n = it * 64 + lane;
    float xv = xT[(size_t)b * NDIM + n];
    #pragma unroll
    for (int o = 0; o < ODIM; ++o) p[o] += xv * h2o_w[o * NDIM + n];
  }
  #pragma unroll
  for (int o = 0; o < ODIM; ++o) {
    float v = p[o];
    #pragma unroll
    for (int off = 32; off >= 1; off >>= 1) v += __shfl_down(v, off, 64);
    if (lane == 0) out[b * ODIM + o] = v + h2o_b[o];
  }
}

__global__ void horn_fail(float* out) {    // loud sentinel if ws too small
  int i = blockIdx.x * 256 + threadIdx.x;
  if (i < BATCH_N * ODIM) out[i] = 12345.0f;
}

extern "C" void kernel_launch(void* const* d_in, const int* in_sizes, int n_in,
                              void* d_out, int out_size, void* d_ws, size_t ws_size,
                              hipStream_t stream) {
  const float* batch = (const float*)d_in[0];
  const float* i2h_w = (const float*)d_in[1];
  const float* i2h_b = (const float*)d_in[2];
  const float* h2h_w = (const float*)d_in[3];
  const float* h2h_b = (const float*)d_in[4];
  const float* h2o_w = (const float*)d_in[5];
  const float* h2o_b = (const float*)d_in[6];
  float* out = (float*)d_out;
  char* ws = (char*)d_ws;

  if (ws_size < WS_NEED) {
    horn_fail<<<16, 256, 0, stream>>>(out);
    return;
  }

  (void)hipFuncSetAttribute(reinterpret_cast<const void*>(horn_persistent),
                            hipFuncAttributeMaxDynamicSharedMemorySize, 65536);

  hipMemsetAsync(ws + YBUF_OFF, 0, YBUF_HALF, stream);   // y_0 = 0 (parity 0)
  hipMemsetAsync(ws + FLG_OFF, 0, FLG_BYTES, stream);    // flags = 0

  horn_convert<<<8192, 256, 0, stream>>>(batch, (unsigned short*)(ws + 0));

  horn_persistent<<<128, THREADS, 65536, stream>>>(
      (const unsigned short*)(ws + 0), i2h_w, i2h_b, h2h_w, h2h_b,
      (unsigned short*)(ws + YBUF_OFF), (unsigned int*)(ws + FLG_OFF),
      (float*)(ws + XT_OFF));

  horn_out<<<BATCH_N, 64, 0, stream>>>((const float*)(ws + XT_OFF), h2o_w, h2o_b, out);
}